// Round 2
// baseline (830.871 us; speedup 1.0000x reference)
//
#include <hip/hip_runtime.h>

typedef __bf16 bf16;
typedef bf16 bf16x8 __attribute__((ext_vector_type(8)));
typedef bf16 bf16x4 __attribute__((ext_vector_type(4)));
typedef float f32x4 __attribute__((ext_vector_type(4)));

constexpr int NN = 8192;   // nodes
constexpr int DD = 512;    // gnn dim
constexpr size_t PSZB = (size_t)NN * DD * 2;   // 8 MB, one bf16 [NN][DD] buffer
constexpr size_t PSZE = (size_t)NN * DD;       // elements

static __device__ inline bf16x8 cvt8(const float* __restrict__ p) {
  f32x4 a = *(const f32x4*)p;
  f32x4 b = *(const f32x4*)(p + 4);
  bf16x8 r;
  r[0] = (bf16)a[0]; r[1] = (bf16)a[1]; r[2] = (bf16)a[2]; r[3] = (bf16)a[3];
  r[4] = (bf16)b[0]; r[5] = (bf16)b[1]; r[6] = (bf16)b[2]; r[7] = (bf16)b[3];
  return r;
}

// async global->LDS, 16B per lane, dest = wave-uniform base + lane*16
#define GLDS(g, l) __builtin_amdgcn_global_load_lds( \
    (const __attribute__((address_space(1))) unsigned int*)(const void*)(g), \
    (__attribute__((address_space(3))) unsigned int*)(void*)(l), 16, 0, 0)

// ---------------- converts ----------------

__global__ __launch_bounds__(256) void convert_w_kernel(
    const float* __restrict__ a, const float* __restrict__ b,
    bf16* __restrict__ ao, bf16* __restrict__ bo) {
  int i8 = ((int)blockIdx.x * 256 + (int)threadIdx.x) * 8;
  if (i8 < DD * DD) {
    *(bf16x8*)&ao[i8] = cvt8(a + i8);
  } else {
    int j = i8 - DD * DD;
    *(bf16x8*)&bo[j] = cvt8(b + j);
  }
}

__global__ __launch_bounds__(256) void convert_adj_kernel(
    const float* __restrict__ a, bf16* __restrict__ o) {
  size_t i8 = ((size_t)blockIdx.x * 256 + threadIdx.x) * 8;
  *(bf16x8*)&o[i8] = cvt8(a + i8);
}

// labels f32 [NN][DD] -> xb bf16 [NN][DD] and xbT bf16 [DD][NN] (64x64 LDS tiles)
__global__ __launch_bounds__(256) void convert_x_kernel(
    const float* __restrict__ src, bf16* __restrict__ xb, bf16* __restrict__ xbT) {
  __shared__ __align__(16) float tile[64][68];
  const int tid = (int)threadIdx.x;
  const int r0 = (int)blockIdx.x * 64;
  const int c0 = (int)blockIdx.y * 64;
#pragma unroll
  for (int p = 0; p < 4; ++p) {
    int row = p * 16 + (tid >> 4);
    int col = (tid & 15) * 4;
    *(f32x4*)&tile[row][col] = *(const f32x4*)&src[(size_t)(r0 + row) * DD + c0 + col];
  }
  __syncthreads();
#pragma unroll
  for (int p = 0; p < 4; ++p) {
    int row = p * 16 + (tid >> 4);
    int col = (tid & 15) * 4;
    f32x4 v = *(const f32x4*)&tile[row][col];
    bf16x4 o;
    o[0] = (bf16)v[0]; o[1] = (bf16)v[1]; o[2] = (bf16)v[2]; o[3] = (bf16)v[3];
    *(bf16x4*)&xb[(size_t)(r0 + row) * DD + c0 + col] = o;
  }
  {
    int c = tid >> 2;
    int rp = (tid & 3) * 16;
    bf16x8 o0, o1;
#pragma unroll
    for (int j = 0; j < 8; ++j) o0[j] = (bf16)tile[rp + j][c];
#pragma unroll
    for (int j = 0; j < 8; ++j) o1[j] = (bf16)tile[rp + 8 + j][c];
    *(bf16x8*)&xbT[(size_t)(c0 + c) * NN + r0 + rp] = o0;
    *(bf16x8*)&xbT[(size_t)(c0 + c) * NN + r0 + rp + 8] = o1;
  }
}

// ---------------- GEMM1: P_s[NN][DD] = bf16( adj[:, ks:ke] @ x[ks:ke, :] ) ----------------
// BM=128, BN=512 (full), split-K over ns partials. 1024 threads, 16 waves (2x8),
// wave tile 64x64, mfma 16x16x32 bf16, GLDS-direct staging, 80KB LDS.
__global__ __launch_bounds__(1024, 4)
void gemm1_kernel(const bf16* __restrict__ adjb, const bf16* __restrict__ xbT,
                  bf16* __restrict__ pbase, int ns) {
  __shared__ __align__(16) bf16 lds_a[128 * 64];   // 16 KB
  __shared__ __align__(16) bf16 lds_b[512 * 64];   // 64 KB
  const int bid = (int)blockIdx.x;
  int split, panel, kb, ksteps;
  if (ns == 4) {
    split = (bid & 7) >> 1;                 // 2 XCDs per split -> B K-slice L2-resident
    panel = (bid >> 3) * 2 + (bid & 1);
    kb = split * 2048; ksteps = 32;
  } else {
    split = bid >> 6;
    panel = bid & 63;
    kb = split * 2752; ksteps = (split < 2) ? 43 : 42;
  }
  bf16* __restrict__ P = pbase + (size_t)split * PSZE;
  const int tid  = (int)threadIdx.x;
  const int lane = tid & 63;
  const int wave = tid >> 6;        // 0..15
  const int wr = wave >> 3;         // 0..1  (64 rows each)
  const int wc = wave & 7;          // 0..7  (64 cols each)
  const int r0 = panel * 128;
  const int fr = lane & 15, fq = lane >> 4;
  const int srow = lane >> 3, scol = (lane & 7) * 8;

  f32x4 acc[4][4] = {};

  for (int kt = 0; kt < ksteps; ++kt) {
    const int k0 = kb + kt * 64;
    // stage A: 16 chunks of 8 rows x 64k (1KB); chunk = wave
    GLDS(adjb + (size_t)(r0 + wave * 8 + srow) * NN + k0 + scol, &lds_a[wave * 512]);
    // stage B: 64 chunks; wave handles 4
#pragma unroll
    for (int c = 0; c < 4; ++c) {
      int chunk = wave * 4 + c;
      GLDS(xbT + (size_t)(chunk * 8 + srow) * NN + k0 + scol, &lds_b[chunk * 512]);
    }
    __syncthreads();
    bf16x8 af[2][4], bv[2][4];
#pragma unroll
    for (int kk = 0; kk < 2; ++kk) {
#pragma unroll
      for (int m = 0; m < 4; ++m)
        af[kk][m] = *(const bf16x8*)&lds_a[(wr * 64 + m * 16 + fr) * 64 + kk * 32 + fq * 8];
#pragma unroll
      for (int n = 0; n < 4; ++n)
        bv[kk][n] = *(const bf16x8*)&lds_b[(wc * 64 + n * 16 + fr) * 64 + kk * 32 + fq * 8];
    }
#pragma unroll
    for (int kk = 0; kk < 2; ++kk)
#pragma unroll
      for (int m = 0; m < 4; ++m)
#pragma unroll
        for (int n = 0; n < 4; ++n)
          acc[m][n] = __builtin_amdgcn_mfma_f32_16x16x32_bf16(af[kk][m], bv[kk][n], acc[m][n], 0, 0, 0);
    __syncthreads();
  }
  // epilogue: C/D layout col=lane&15, row=(lane>>4)*4+reg
#pragma unroll
  for (int m = 0; m < 4; ++m)
#pragma unroll
    for (int n = 0; n < 4; ++n)
#pragma unroll
      for (int r = 0; r < 4; ++r) {
        int row = r0 + wr * 64 + m * 16 + fq * 4 + r;
        int col = wc * 64 + n * 16 + fr;
        P[(size_t)row * DD + col] = (bf16)acc[m][n][r];
      }
}

// ---------------- GEMM2 (transposed): x_new^T = relu(Ws@x^T + sum_s Wn@P_s^T + b)^T --------
// M = 512 (d_out, full per block), N = 32-node panel, K = 512*(1+ns).
// Each block exclusively owns its 32 xb rows -> in-place xb update is race-free.
// Writes xbT directly (it IS x_new^T) and xb via LDS transpose.
__global__ __launch_bounds__(1024, 4)
void gemm2_kernel(const bf16* __restrict__ wsb, const bf16* __restrict__ wnb,
                  bf16* __restrict__ xb, const bf16* __restrict__ pbase, int ns,
                  const float* __restrict__ bself, bf16* __restrict__ xbT) {
  __shared__ __align__(16) char smem[69632];
  bf16* lds_a = (bf16*)smem;             // W tile [512][64], 64 KB
  bf16* lds_b = (bf16*)(smem + 65536);   // x/P tile [32][64], 4 KB
  const int tid  = (int)threadIdx.x;
  const int lane = tid & 63;
  const int wave = tid >> 6;             // 0..15 -> d_out rows wave*32..+31
  const int n0 = (int)blockIdx.x * 32;
  const int fr = lane & 15, fq = lane >> 4;
  const int srow = lane >> 3, scol = (lane & 7) * 8;

  f32x4 acc[2][2] = {};

  for (int pr = 0; pr <= ns; ++pr) {
    const bf16* __restrict__ A = pr ? wnb : wsb;                       // [512][512]
    const bf16* __restrict__ B = pr ? pbase + (size_t)(pr - 1) * PSZE : xb;  // [NN][DD]
    for (int kt = 0; kt < DD / 64; ++kt) {
      const int k0 = kt * 64;
#pragma unroll
      for (int c = 0; c < 4; ++c) {
        int chunk = wave * 4 + c;
        GLDS(A + (size_t)(chunk * 8 + srow) * DD + k0 + scol, &lds_a[chunk * 512]);
      }
      if (wave < 4)
        GLDS(B + (size_t)(n0 + wave * 8 + srow) * DD + k0 + scol, &lds_b[wave * 512]);
      __syncthreads();
      bf16x8 af[2][2], bv[2][2];
#pragma unroll
      for (int kk = 0; kk < 2; ++kk) {
#pragma unroll
        for (int m = 0; m < 2; ++m)
          af[kk][m] = *(const bf16x8*)&lds_a[(wave * 32 + m * 16 + fr) * 64 + kk * 32 + fq * 8];
#pragma unroll
        for (int n = 0; n < 2; ++n)
          bv[kk][n] = *(const bf16x8*)&lds_b[(n * 16 + fr) * 64 + kk * 32 + fq * 8];
      }
#pragma unroll
      for (int kk = 0; kk < 2; ++kk)
#pragma unroll
        for (int m = 0; m < 2; ++m)
#pragma unroll
          for (int n = 0; n < 2; ++n)
            acc[m][n] = __builtin_amdgcn_mfma_f32_16x16x32_bf16(af[kk][m], bv[kk][n], acc[m][n], 0, 0, 0);
      __syncthreads();
    }
  }
  // epilogue: C'[d][node]; d = wave*32+m*16+fq*4+r, node = n0 + n*16+fr
  bf16* lds_t = (bf16*)smem;  // [32 node][520 d]
#pragma unroll
  for (int m = 0; m < 2; ++m)
#pragma unroll
    for (int n = 0; n < 2; ++n)
#pragma unroll
      for (int r = 0; r < 4; ++r) {
        int d = wave * 32 + m * 16 + fq * 4 + r;
        int node = n * 16 + fr;
        float v = acc[m][n][r] + bself[d];
        v = v > 0.f ? v : 0.f;
        bf16 h = (bf16)v;
        xbT[(size_t)d * NN + n0 + node] = h;
        lds_t[node * 520 + d] = h;
      }
  __syncthreads();
  {
    int node = tid >> 5;
    int dc = (tid & 31) * 16;
    bf16x8 v0 = *(const bf16x8*)&lds_t[node * 520 + dc];
    bf16x8 v1 = *(const bf16x8*)&lds_t[node * 520 + dc + 8];
    *(bf16x8*)&xb[(size_t)(n0 + node) * DD + dc] = v0;
    *(bf16x8*)&xb[(size_t)(n0 + node) * DD + dc + 8] = v1;
  }
}

// ---------------- pooling + head ----------------

__global__ __launch_bounds__(256) void pool_kernel(
    const bf16* __restrict__ xb, float* __restrict__ pooled) {
  const int t = (int)threadIdx.x;
  const int r0 = (int)blockIdx.x * 32;
  float s0 = 0.f, s1 = 0.f;
  for (int r = 0; r < 32; ++r) {
    s0 += (float)xb[(size_t)(r0 + r) * DD + t];
    s1 += (float)xb[(size_t)(r0 + r) * DD + t + 256];
  }
  atomicAdd(&pooled[t], s0);
  atomicAdd(&pooled[t + 256], s1);
}

__global__ __launch_bounds__(64) void final_kernel(
    const float* __restrict__ pooled, const float* __restrict__ features,
    const float* __restrict__ wfc, const float* __restrict__ bfc,
    float* __restrict__ out) {
  const int t = (int)threadIdx.x;
  float s = 0.f;
  for (int i = t; i < DD + 64; i += 64) {
    float v = (i < DD) ? pooled[i] * (1.0f / (float)NN) : features[i - DD];
    s += v * wfc[i];
  }
#pragma unroll
  for (int off = 32; off > 0; off >>= 1) s += __shfl_down(s, off);
  if (t == 0) {
    float z = s + bfc[0];
    out[0] = 1.0f / (1.0f + expf(-z));
  }
}

// ---------------- launch ----------------

extern "C" void kernel_launch(void* const* d_in, const int* in_sizes, int n_in,
                              void* d_out, int out_size, void* d_ws, size_t ws_size,
                              hipStream_t stream) {
  const float* labels   = (const float*)d_in[0];
  const float* adj      = (const float*)d_in[1];
  const float* features = (const float*)d_in[2];
  const float* W_self   = (const float*)d_in[3];
  const float* b_self   = (const float*)d_in[4];
  const float* W_neigh  = (const float*)d_in[5];
  const float* W_fc     = (const float*)d_in[6];
  const float* b_fc     = (const float*)d_in[7];
  float* out = (float*)d_out;

  char* ws = (char*)d_ws;
  // need(ns) = (2+ns)*PSZB + 1MB(W) + 4KB(pool) + 128MB(adjb)
  const size_t NEED4 = 6 * PSZB + 1048576 + 4096 + 134217728;  // 185,602,048
  const int ns = (ws_size >= NEED4) ? 4 : 3;                   // need(3)=177,213,440 (proven)

  bf16*  xb    = (bf16*)(ws);
  bf16*  xbT   = (bf16*)(ws + PSZB);
  bf16*  pbase = (bf16*)(ws + 2 * PSZB);
  char*  after_p = ws + (size_t)(2 + ns) * PSZB;
  bf16*  wsb    = (bf16*)(after_p);
  bf16*  wnb    = (bf16*)(after_p + 524288);
  float* pooled = (float*)(after_p + 1048576);
  bf16*  adjb   = (bf16*)(after_p + 1048576 + 4096);

  convert_w_kernel<<<2 * DD * DD / 8 / 256, 256, 0, stream>>>(W_self, W_neigh, wsb, wnb);
  convert_adj_kernel<<<(int)((size_t)NN * NN / 8 / 256), 256, 0, stream>>>(adj, adjb);
  convert_x_kernel<<<dim3(NN / 64, DD / 64), 256, 0, stream>>>(labels, xb, xbT);

  for (int it = 0; it < 4; ++it) {
    gemm1_kernel<<<ns * 64, 1024, 0, stream>>>(adjb, xbT, pbase, ns);
    gemm2_kernel<<<NN / 32, 1024, 0, stream>>>(wsb, wnb, xb, pbase, ns, b_self, xbT);
  }

  hipMemsetAsync(pooled, 0, DD * sizeof(float), stream);
  pool_kernel<<<NN / 32, 256, 0, stream>>>(xb, pooled);
  final_kernel<<<1, 64, 0, stream>>>(pooled, features, W_fc, b_fc, out);
}

// Round 3
// 626.607 us; speedup vs baseline: 1.3260x; 1.3260x over previous
//
#include <hip/hip_runtime.h>

typedef __bf16 bf16;
typedef bf16 bf16x8 __attribute__((ext_vector_type(8)));
typedef bf16 bf16x4 __attribute__((ext_vector_type(4)));
typedef float f32x4 __attribute__((ext_vector_type(4)));

constexpr int NN = 8192;   // nodes
constexpr int DD = 512;    // gnn dim
constexpr size_t PSZB = (size_t)NN * DD * 2;   // 8 MB, one bf16 [NN][DD] buffer
constexpr size_t PSZE = (size_t)NN * DD;       // elements
constexpr int NS = 4;                          // split-K factor (ws_size = 1 GiB, plenty)

static __device__ inline bf16x8 cvt8(const float* __restrict__ p) {
  f32x4 a = *(const f32x4*)p;
  f32x4 b = *(const f32x4*)(p + 4);
  bf16x8 r;
  r[0] = (bf16)a[0]; r[1] = (bf16)a[1]; r[2] = (bf16)a[2]; r[3] = (bf16)a[3];
  r[4] = (bf16)b[0]; r[5] = (bf16)b[1]; r[6] = (bf16)b[2]; r[7] = (bf16)b[3];
  return r;
}

// async global->LDS, 16B per lane, dest = wave-uniform base + lane*16
#define GLDS(g, l) __builtin_amdgcn_global_load_lds( \
    (const __attribute__((address_space(1))) unsigned int*)(const void*)(g), \
    (__attribute__((address_space(3))) unsigned int*)(void*)(l), 16, 0, 0)

// ---------------- converts ----------------

__global__ __launch_bounds__(256) void convert_w_kernel(
    const float* __restrict__ a, const float* __restrict__ b,
    bf16* __restrict__ ao, bf16* __restrict__ bo) {
  int i8 = ((int)blockIdx.x * 256 + (int)threadIdx.x) * 8;
  if (i8 < DD * DD) {
    *(bf16x8*)&ao[i8] = cvt8(a + i8);
  } else {
    int j = i8 - DD * DD;
    *(bf16x8*)&bo[j] = cvt8(b + j);
  }
}

__global__ __launch_bounds__(256) void convert_adj_kernel(
    const float* __restrict__ a, bf16* __restrict__ o) {
  size_t i8 = ((size_t)blockIdx.x * 256 + threadIdx.x) * 8;
  *(bf16x8*)&o[i8] = cvt8(a + i8);
}

// labels f32 [NN][DD] -> xb bf16 [NN][DD] and xbT bf16 [DD][NN] (64x64 LDS tiles)
__global__ __launch_bounds__(256) void convert_x_kernel(
    const float* __restrict__ src, bf16* __restrict__ xb, bf16* __restrict__ xbT) {
  __shared__ __align__(16) float tile[64][68];
  const int tid = (int)threadIdx.x;
  const int r0 = (int)blockIdx.x * 64;
  const int c0 = (int)blockIdx.y * 64;
#pragma unroll
  for (int p = 0; p < 4; ++p) {
    int row = p * 16 + (tid >> 4);
    int col = (tid & 15) * 4;
    *(f32x4*)&tile[row][col] = *(const f32x4*)&src[(size_t)(r0 + row) * DD + c0 + col];
  }
  __syncthreads();
#pragma unroll
  for (int p = 0; p < 4; ++p) {
    int row = p * 16 + (tid >> 4);
    int col = (tid & 15) * 4;
    f32x4 v = *(const f32x4*)&tile[row][col];
    bf16x4 o;
    o[0] = (bf16)v[0]; o[1] = (bf16)v[1]; o[2] = (bf16)v[2]; o[3] = (bf16)v[3];
    *(bf16x4*)&xb[(size_t)(r0 + row) * DD + c0 + col] = o;
  }
  {
    int c = tid >> 2;
    int rp = (tid & 3) * 16;
    bf16x8 o0, o1;
#pragma unroll
    for (int j = 0; j < 8; ++j) o0[j] = (bf16)tile[rp + j][c];
#pragma unroll
    for (int j = 0; j < 8; ++j) o1[j] = (bf16)tile[rp + 8 + j][c];
    *(bf16x8*)&xbT[(size_t)(c0 + c) * NN + r0 + rp] = o0;
    *(bf16x8*)&xbT[(size_t)(c0 + c) * NN + r0 + rp + 8] = o1;
  }
}

// ---------------- GEMM1: P_s[NN][DD] = bf16( adj[:, ks:ke] @ x[ks:ke, :] ) ----------------
// 8-phase-style schedule: BM=BN=256, BK=64, 512 thr (8 waves 2Mx4N), split-K=4.
// 4 phases per K-tile, 1 half-tile (16KB) prefetch per phase, counted vmcnt(8/10),
// T2 swizzle baked into GLDS source column + XOR'd read slot. LDS 128 KiB dbuf.

// stage one 128x64 half-tile from g[grow0+r][k0+c] (row stride NN) into smbase (linear)
__device__ __forceinline__ void stage_half(const bf16* __restrict__ g, int grow0, int k0,
                                           bf16* smbase, int wave, int lane) {
#pragma unroll
  for (int i = 0; i < 2; ++i) {
    int c = wave * 2 + i;                                  // chunk 0..15, 1 KB each
    int row = grow0 + c * 8 + (lane >> 3);
    int col = k0 + (((lane & 7) ^ ((lane >> 3) & 7)) << 3);  // pre-swizzled source slot
    GLDS(g + (size_t)row * NN + col, smbase + c * 512);
  }
}

__global__ __launch_bounds__(512, 2)
void gemm1_kernel(const bf16* __restrict__ adjb, const bf16* __restrict__ xbT,
                  bf16* __restrict__ pbase) {
  __shared__ __align__(16) bf16 sm[65536];   // [par][A 16384 | B 16384], 128 KiB
  const int bid  = (int)blockIdx.x;
  const int p    = bid >> 3;            // panel 0..31
  const int s    = (bid >> 1) & 3;      // split 0..3  (XCD pair shares split+col)
  const int cb   = bid & 1;             // col block 0..1
  const int prow0 = p * 256;
  const int bcol0 = cb * 256;
  const int kb    = s * 2048;           // 32 K-tiles of 64
  bf16* __restrict__ P = pbase + (size_t)s * PSZE;

  const int tid  = (int)threadIdx.x;
  const int lane = tid & 63;
  const int wave = tid >> 6;            // 0..7
  const int wr   = wave >> 2;           // 0..1
  const int wc   = wave & 3;            // 0..3
  const int fr   = lane & 15, fq = lane >> 4;

  f32x4 acc[8][4] = {};

#define A_OFF(par) ((par) * 32768)
#define B_OFF(par) ((par) * 32768 + 16384)
#define STAGE_A(tile, half, par) \
  stage_half(adjb, prow0 + (half) * 128, kb + ((tile) & 31) * 64, \
             sm + A_OFF(par) + (half) * 8192, wave, lane)
#define STAGE_B(tile, half, par) \
  stage_half(xbT, bcol0 + (half) * 128, kb + ((tile) & 31) * 64, \
             sm + B_OFF(par) + (half) * 8192, wave, lane)

  // prologue: tiles 0 (par0) fully + tile 1 (par1) except Ah1. Issue order matters.
  STAGE_B(0, 0, 0); STAGE_B(0, 1, 0); STAGE_A(0, 0, 0); STAGE_A(0, 1, 0);
  STAGE_B(1, 0, 1); STAGE_B(1, 1, 1); STAGE_A(1, 0, 1);

  bf16x8 bv[2][4], af[2][2];

#define LOAD_B(par)                                                        \
  _Pragma("unroll") for (int kk = 0; kk < 2; ++kk)                         \
  _Pragma("unroll") for (int n = 0; n < 4; ++n) {                          \
    int rowl = wc * 64 + n * 16 + fr;                                      \
    int slot = (kk * 4 + fq) ^ (rowl & 7);                                 \
    bv[kk][n] = *(const bf16x8*)&sm[B_OFF(par) + rowl * 64 + slot * 8];    \
  }
#define LOAD_A(q, par)                                                     \
  _Pragma("unroll") for (int kk = 0; kk < 2; ++kk)                         \
  _Pragma("unroll") for (int j = 0; j < 2; ++j) {                          \
    int rowl = (q) * 64 + wr * 32 + j * 16 + fr;                           \
    int slot = (kk * 4 + fq) ^ (rowl & 7);                                 \
    af[kk][j] = *(const bf16x8*)&sm[A_OFF(par) + rowl * 64 + slot * 8];    \
  }
#define QMFMA(q)                                                           \
  __builtin_amdgcn_s_setprio(1);                                           \
  _Pragma("unroll") for (int kk = 0; kk < 2; ++kk)                         \
  _Pragma("unroll") for (int j = 0; j < 2; ++j)                            \
  _Pragma("unroll") for (int n = 0; n < 4; ++n)                            \
    acc[2 * (q) + j][n] = __builtin_amdgcn_mfma_f32_16x16x32_bf16(         \
        af[kk][j], bv[kk][n], acc[2 * (q) + j][n], 0, 0, 0);               \
  __builtin_amdgcn_s_setprio(0);
#define BARRIER() __builtin_amdgcn_s_barrier(); __builtin_amdgcn_sched_barrier(0)

  int par = 0;
  for (int t = 0; t < 32; ++t, par ^= 1) {
    // ---- P1: read all B + A q0; stage Ah1(t+1) into other buffer ----
    asm volatile("s_waitcnt vmcnt(8)" ::: "memory");
    BARRIER();
    LOAD_B(par);
    LOAD_A(0, par);
    STAGE_A(t + 1, 1, par ^ 1);
    QMFMA(0);
    // ---- P2: A q1; stage Bh0(t+2) (B region of this par is dead after P1) ----
    BARRIER();
    LOAD_A(1, par);
    STAGE_B(t + 2, 0, par);
    QMFMA(1);
    // ---- P3: A q2 (needs Ah1(t), staged 4 phases ago); stage Bh1(t+2) ----
    asm volatile("s_waitcnt vmcnt(10)" ::: "memory");
    BARRIER();
    LOAD_A(2, par);
    STAGE_B(t + 2, 1, par);
    QMFMA(2);
    // ---- P4: A q3; stage Ah0(t+2) (A rows 0-127 dead after P2) ----
    BARRIER();
    LOAD_A(3, par);
    STAGE_A(t + 2, 0, par);
    QMFMA(3);
  }

  // epilogue: C/D frag layout col=lane&15, row=(lane>>4)*4+reg
#pragma unroll
  for (int m = 0; m < 8; ++m)
#pragma unroll
    for (int n = 0; n < 4; ++n)
#pragma unroll
      for (int r = 0; r < 4; ++r) {
        int row = prow0 + (m >> 1) * 64 + wr * 32 + (m & 1) * 16 + fq * 4 + r;
        int col = bcol0 + wc * 64 + n * 16 + fr;
        P[(size_t)row * DD + col] = (bf16)acc[m][n][r];
      }
#undef A_OFF
#undef B_OFF
#undef STAGE_A
#undef STAGE_B
#undef LOAD_A
#undef LOAD_B
#undef QMFMA
#undef BARRIER
}

// ---------------- GEMM2 (transposed): x_new^T = relu(Ws@x^T + sum_s Wn@P_s^T + b)^T --------
// M = 512 (d_out, full per block), N = 32-node panel, K = 512*(1+NS).
__global__ __launch_bounds__(1024, 4)
void gemm2_kernel(const bf16* __restrict__ wsb, const bf16* __restrict__ wnb,
                  bf16* __restrict__ xb, const bf16* __restrict__ pbase,
                  const float* __restrict__ bself, bf16* __restrict__ xbT) {
  __shared__ __align__(16) char smem[69632];
  bf16* lds_a = (bf16*)smem;             // W tile [512][64], 64 KB
  bf16* lds_b = (bf16*)(smem + 65536);   // x/P tile [32][64], 4 KB
  const int tid  = (int)threadIdx.x;
  const int lane = tid & 63;
  const int wave = tid >> 6;             // 0..15 -> d_out rows wave*32..+31
  const int n0 = (int)blockIdx.x * 32;
  const int fr = lane & 15, fq = lane >> 4;
  const int srow = lane >> 3, scol = (lane & 7) * 8;

  f32x4 acc[2][2] = {};

  for (int pr = 0; pr <= NS; ++pr) {
    const bf16* __restrict__ A = pr ? wnb : wsb;                             // [512][512]
    const bf16* __restrict__ B = pr ? pbase + (size_t)(pr - 1) * PSZE : xb;  // [NN][DD]
    for (int kt = 0; kt < DD / 64; ++kt) {
      const int k0 = kt * 64;
#pragma unroll
      for (int c = 0; c < 4; ++c) {
        int chunk = wave * 4 + c;
        GLDS(A + (size_t)(chunk * 8 + srow) * DD + k0 + scol, &lds_a[chunk * 512]);
      }
      if (wave < 4)
        GLDS(B + (size_t)(n0 + wave * 8 + srow) * DD + k0 + scol, &lds_b[wave * 512]);
      __syncthreads();
      bf16x8 af[2][2], bv[2][2];
#pragma unroll
      for (int kk = 0; kk < 2; ++kk) {
#pragma unroll
        for (int m = 0; m < 2; ++m)
          af[kk][m] = *(const bf16x8*)&lds_a[(wave * 32 + m * 16 + fr) * 64 + kk * 32 + fq * 8];
#pragma unroll
        for (int n = 0; n < 2; ++n)
          bv[kk][n] = *(const bf16x8*)&lds_b[(n * 16 + fr) * 64 + kk * 32 + fq * 8];
      }
#pragma unroll
      for (int kk = 0; kk < 2; ++kk)
#pragma unroll
        for (int m = 0; m < 2; ++m)
#pragma unroll
          for (int n = 0; n < 2; ++n)
            acc[m][n] = __builtin_amdgcn_mfma_f32_16x16x32_bf16(af[kk][m], bv[kk][n], acc[m][n], 0, 0, 0);
      __syncthreads();
    }
  }
  // epilogue: C'[d][node]; d = wave*32+m*16+fq*4+r, node = n0 + n*16+fr
  bf16* lds_t = (bf16*)smem;  // [32 node][520 d]
#pragma unroll
  for (int m = 0; m < 2; ++m)
#pragma unroll
    for (int n = 0; n < 2; ++n)
#pragma unroll
      for (int r = 0; r < 4; ++r) {
        int d = wave * 32 + m * 16 + fq * 4 + r;
        int node = n * 16 + fr;
        float v = acc[m][n][r] + bself[d];
        v = v > 0.f ? v : 0.f;
        bf16 h = (bf16)v;
        xbT[(size_t)d * NN + n0 + node] = h;
        lds_t[node * 520 + d] = h;
      }
  __syncthreads();
  {
    int node = tid >> 5;
    int dc = (tid & 31) * 16;
    bf16x8 v0 = *(const bf16x8*)&lds_t[node * 520 + dc];
    bf16x8 v1 = *(const bf16x8*)&lds_t[node * 520 + dc + 8];
    *(bf16x8*)&xb[(size_t)(n0 + node) * DD + dc] = v0;
    *(bf16x8*)&xb[(size_t)(n0 + node) * DD + dc + 8] = v1;
  }
}

// ---------------- pooling + head ----------------

__global__ __launch_bounds__(256) void pool_kernel(
    const bf16* __restrict__ xb, float* __restrict__ pooled) {
  const int t = (int)threadIdx.x;
  const int r0 = (int)blockIdx.x * 32;
  float s0 = 0.f, s1 = 0.f;
  for (int r = 0; r < 32; ++r) {
    s0 += (float)xb[(size_t)(r0 + r) * DD + t];
    s1 += (float)xb[(size_t)(r0 + r) * DD + t + 256];
  }
  atomicAdd(&pooled[t], s0);
  atomicAdd(&pooled[t + 256], s1);
}

__global__ __launch_bounds__(64) void final_kernel(
    const float* __restrict__ pooled, const float* __restrict__ features,
    const float* __restrict__ wfc, const float* __restrict__ bfc,
    float* __restrict__ out) {
  const int t = (int)threadIdx.x;
  float s = 0.f;
  for (int i = t; i < DD + 64; i += 64) {
    float v = (i < DD) ? pooled[i] * (1.0f / (float)NN) : features[i - DD];
    s += v * wfc[i];
  }
#pragma unroll
  for (int off = 32; off > 0; off >>= 1) s += __shfl_down(s, off);
  if (t == 0) {
    float z = s + bfc[0];
    out[0] = 1.0f / (1.0f + expf(-z));
  }
}

// ---------------- launch ----------------

extern "C" void kernel_launch(void* const* d_in, const int* in_sizes, int n_in,
                              void* d_out, int out_size, void* d_ws, size_t ws_size,
                              hipStream_t stream) {
  const float* labels   = (const float*)d_in[0];
  const float* adj      = (const float*)d_in[1];
  const float* features = (const float*)d_in[2];
  const float* W_self   = (const float*)d_in[3];
  const float* b_self   = (const float*)d_in[4];
  const float* W_neigh  = (const float*)d_in[5];
  const float* W_fc     = (const float*)d_in[6];
  const float* b_fc     = (const float*)d_in[7];
  float* out = (float*)d_out;

  char* ws = (char*)d_ws;   // ws_size = 1 GiB (observed); layout needs ~185.6 MB
  bf16*  xb    = (bf16*)(ws);
  bf16*  xbT   = (bf16*)(ws + PSZB);
  bf16*  pbase = (bf16*)(ws + 2 * PSZB);
  char*  after_p = ws + (size_t)(2 + NS) * PSZB;
  bf16*  wsb    = (bf16*)(after_p);
  bf16*  wnb    = (bf16*)(after_p + 524288);
  float* pooled = (float*)(after_p + 1048576);
  bf16*  adjb   = (bf16*)(after_p + 1048576 + 4096);

  convert_w_kernel<<<2 * DD * DD / 8 / 256, 256, 0, stream>>>(W_self, W_neigh, wsb, wnb);
  convert_adj_kernel<<<(int)((size_t)NN * NN / 8 / 256), 256, 0, stream>>>(adj, adjb);
  convert_x_kernel<<<dim3(NN / 64, DD / 64), 256, 0, stream>>>(labels, xb, xbT);

  for (int it = 0; it < 4; ++it) {
    gemm1_kernel<<<256, 512, 0, stream>>>(adjb, xbT, pbase);
    gemm2_kernel<<<NN / 32, 1024, 0, stream>>>(wsb, wnb, xb, pbase, b_self, xbT);
  }

  hipMemsetAsync(pooled, 0, DD * sizeof(float), stream);
  pool_kernel<<<NN / 32, 256, 0, stream>>>(xb, pooled);
  final_kernel<<<1, 64, 0, stream>>>(pooled, features, W_fc, b_fc, out);
}

// Round 4
// 451.860 us; speedup vs baseline: 1.8388x; 1.3867x over previous
//
#include <hip/hip_runtime.h>

typedef __bf16 bf16;
typedef bf16 bf16x8 __attribute__((ext_vector_type(8)));
typedef bf16 bf16x4 __attribute__((ext_vector_type(4)));
typedef float f32x4 __attribute__((ext_vector_type(4)));

constexpr int NN = 8192;   // nodes
constexpr int DD = 512;    // gnn dim
constexpr size_t PSZB = (size_t)NN * DD * 2;   // 8 MB, one bf16 [NN][DD] buffer
constexpr size_t PSZE = (size_t)NN * DD;       // elements
constexpr int NS = 4;                          // split-K factor (ws_size = 1 GiB)

static __device__ inline bf16x8 cvt8(const float* __restrict__ p) {
  f32x4 a = *(const f32x4*)p;
  f32x4 b = *(const f32x4*)(p + 4);
  bf16x8 r;
  r[0] = (bf16)a[0]; r[1] = (bf16)a[1]; r[2] = (bf16)a[2]; r[3] = (bf16)a[3];
  r[4] = (bf16)b[0]; r[5] = (bf16)b[1]; r[6] = (bf16)b[2]; r[7] = (bf16)b[3];
  return r;
}

// async global->LDS, 16B per lane, dest = wave-uniform base + lane*16
#define GLDS(g, l) __builtin_amdgcn_global_load_lds( \
    (const __attribute__((address_space(1))) unsigned int*)(const void*)(g), \
    (__attribute__((address_space(3))) unsigned int*)(void*)(l), 16, 0, 0)

// ---------------- converts ----------------

__global__ __launch_bounds__(256) void convert_w_kernel(
    const float* __restrict__ a, const float* __restrict__ b,
    bf16* __restrict__ ao, bf16* __restrict__ bo) {
  int i8 = ((int)blockIdx.x * 256 + (int)threadIdx.x) * 8;
  if (i8 < DD * DD) {
    *(bf16x8*)&ao[i8] = cvt8(a + i8);
  } else {
    int j = i8 - DD * DD;
    *(bf16x8*)&bo[j] = cvt8(b + j);
  }
}

__global__ __launch_bounds__(256) void convert_adj_kernel(
    const float* __restrict__ a, bf16* __restrict__ o) {
  size_t i8 = ((size_t)blockIdx.x * 256 + threadIdx.x) * 8;
  *(bf16x8*)&o[i8] = cvt8(a + i8);
}

// labels f32 [NN][DD] -> xb bf16 [NN][DD] and xbT bf16 [DD][NN] (64x64 LDS tiles)
__global__ __launch_bounds__(256) void convert_x_kernel(
    const float* __restrict__ src, bf16* __restrict__ xb, bf16* __restrict__ xbT) {
  __shared__ __align__(16) float tile[64][68];
  const int tid = (int)threadIdx.x;
  const int r0 = (int)blockIdx.x * 64;
  const int c0 = (int)blockIdx.y * 64;
#pragma unroll
  for (int p = 0; p < 4; ++p) {
    int row = p * 16 + (tid >> 4);
    int col = (tid & 15) * 4;
    *(f32x4*)&tile[row][col] = *(const f32x4*)&src[(size_t)(r0 + row) * DD + c0 + col];
  }
  __syncthreads();
#pragma unroll
  for (int p = 0; p < 4; ++p) {
    int row = p * 16 + (tid >> 4);
    int col = (tid & 15) * 4;
    f32x4 v = *(const f32x4*)&tile[row][col];
    bf16x4 o;
    o[0] = (bf16)v[0]; o[1] = (bf16)v[1]; o[2] = (bf16)v[2]; o[3] = (bf16)v[3];
    *(bf16x4*)&xb[(size_t)(r0 + row) * DD + c0 + col] = o;
  }
  {
    int c = tid >> 2;
    int rp = (tid & 3) * 16;
    bf16x8 o0, o1;
#pragma unroll
    for (int j = 0; j < 8; ++j) o0[j] = (bf16)tile[rp + j][c];
#pragma unroll
    for (int j = 0; j < 8; ++j) o1[j] = (bf16)tile[rp + 8 + j][c];
    *(bf16x8*)&xbT[(size_t)(c0 + c) * NN + r0 + rp] = o0;
    *(bf16x8*)&xbT[(size_t)(c0 + c) * NN + r0 + rp + 8] = o1;
  }
}

// ---------------- GEMM1: P_s[NN][DD] = bf16( adj[:, ks:ke] @ x[ks:ke, :] ) ----------------
// (unchanged from R3 — working 4-phase dbuf schedule, counted vmcnt, T2 swizzle)

__device__ __forceinline__ void stage_half(const bf16* __restrict__ g, int grow0, int k0,
                                           bf16* smbase, int wave, int lane) {
#pragma unroll
  for (int i = 0; i < 2; ++i) {
    int c = wave * 2 + i;                                  // chunk 0..15, 1 KB each
    int row = grow0 + c * 8 + (lane >> 3);
    int col = k0 + (((lane & 7) ^ ((lane >> 3) & 7)) << 3);  // pre-swizzled source slot
    GLDS(g + (size_t)row * NN + col, smbase + c * 512);
  }
}

__global__ __launch_bounds__(512, 2)
void gemm1_kernel(const bf16* __restrict__ adjb, const bf16* __restrict__ xbT,
                  bf16* __restrict__ pbase) {
  __shared__ __align__(16) bf16 sm[65536];   // [par][A 16384 | B 16384], 128 KiB
  const int bid  = (int)blockIdx.x;
  const int p    = bid >> 3;            // panel 0..31
  const int s    = (bid >> 1) & 3;      // split 0..3  (XCD pair shares split+col)
  const int cb   = bid & 1;             // col block 0..1
  const int prow0 = p * 256;
  const int bcol0 = cb * 256;
  const int kb    = s * 2048;           // 32 K-tiles of 64
  bf16* __restrict__ P = pbase + (size_t)s * PSZE;

  const int tid  = (int)threadIdx.x;
  const int lane = tid & 63;
  const int wave = tid >> 6;            // 0..7
  const int wr   = wave >> 2;           // 0..1
  const int wc   = wave & 3;            // 0..3
  const int fr   = lane & 15, fq = lane >> 4;

  f32x4 acc[8][4] = {};

#define A_OFF(par) ((par) * 32768)
#define B_OFF(par) ((par) * 32768 + 16384)
#define STAGE_A(tile, half, par) \
  stage_half(adjb, prow0 + (half) * 128, kb + ((tile) & 31) * 64, \
             sm + A_OFF(par) + (half) * 8192, wave, lane)
#define STAGE_B(tile, half, par) \
  stage_half(xbT, bcol0 + (half) * 128, kb + ((tile) & 31) * 64, \
             sm + B_OFF(par) + (half) * 8192, wave, lane)

  STAGE_B(0, 0, 0); STAGE_B(0, 1, 0); STAGE_A(0, 0, 0); STAGE_A(0, 1, 0);
  STAGE_B(1, 0, 1); STAGE_B(1, 1, 1); STAGE_A(1, 0, 1);

  bf16x8 bv[2][4], af[2][2];

#define LOAD_B(par)                                                        \
  _Pragma("unroll") for (int kk = 0; kk < 2; ++kk)                         \
  _Pragma("unroll") for (int n = 0; n < 4; ++n) {                          \
    int rowl = wc * 64 + n * 16 + fr;                                      \
    int slot = (kk * 4 + fq) ^ (rowl & 7);                                 \
    bv[kk][n] = *(const bf16x8*)&sm[B_OFF(par) + rowl * 64 + slot * 8];    \
  }
#define LOAD_A(q, par)                                                     \
  _Pragma("unroll") for (int kk = 0; kk < 2; ++kk)                         \
  _Pragma("unroll") for (int j = 0; j < 2; ++j) {                          \
    int rowl = (q) * 64 + wr * 32 + j * 16 + fr;                           \
    int slot = (kk * 4 + fq) ^ (rowl & 7);                                 \
    af[kk][j] = *(const bf16x8*)&sm[A_OFF(par) + rowl * 64 + slot * 8];    \
  }
#define QMFMA(q)                                                           \
  __builtin_amdgcn_s_setprio(1);                                           \
  _Pragma("unroll") for (int kk = 0; kk < 2; ++kk)                         \
  _Pragma("unroll") for (int j = 0; j < 2; ++j)                            \
  _Pragma("unroll") for (int n = 0; n < 4; ++n)                            \
    acc[2 * (q) + j][n] = __builtin_amdgcn_mfma_f32_16x16x32_bf16(         \
        af[kk][j], bv[kk][n], acc[2 * (q) + j][n], 0, 0, 0);               \
  __builtin_amdgcn_s_setprio(0);
#define BARRIER() __builtin_amdgcn_s_barrier(); __builtin_amdgcn_sched_barrier(0)

  int par = 0;
  for (int t = 0; t < 32; ++t, par ^= 1) {
    asm volatile("s_waitcnt vmcnt(8)" ::: "memory");
    BARRIER();
    LOAD_B(par);
    LOAD_A(0, par);
    STAGE_A(t + 1, 1, par ^ 1);
    QMFMA(0);
    BARRIER();
    LOAD_A(1, par);
    STAGE_B(t + 2, 0, par);
    QMFMA(1);
    asm volatile("s_waitcnt vmcnt(10)" ::: "memory");
    BARRIER();
    LOAD_A(2, par);
    STAGE_B(t + 2, 1, par);
    QMFMA(2);
    BARRIER();
    LOAD_A(3, par);
    STAGE_A(t + 2, 0, par);
    QMFMA(3);
  }

#pragma unroll
  for (int m = 0; m < 8; ++m)
#pragma unroll
    for (int n = 0; n < 4; ++n)
#pragma unroll
      for (int r = 0; r < 4; ++r) {
        int row = prow0 + (m >> 1) * 64 + wr * 32 + (m & 1) * 16 + fq * 4 + r;
        int col = bcol0 + wc * 64 + n * 16 + fr;
        P[(size_t)row * DD + col] = (bf16)acc[m][n][r];
      }
#undef A_OFF
#undef B_OFF
#undef STAGE_A
#undef STAGE_B
#undef LOAD_A
#undef LOAD_B
#undef QMFMA
#undef BARRIER
}

// ---------------- GEMM2 (transposed): x_new^T = relu(Ws@x^T + Wn@(sum_s P_s)^T + b)^T ------
// M = 512 (d_out, full per block), N = 32-node panel, K = 1024 (self 512 + neigh 512).
// Split-K reduction folded into neighbor-pass B staging (read 4 partials, f32-sum, ds_write).
// T2 swizzle on both A (pre-swizzled GLDS source) and B (GLDS source / swizzled ds_write).
__global__ __launch_bounds__(1024, 4)
void gemm2_kernel(const bf16* __restrict__ wsb, const bf16* __restrict__ wnb,
                  bf16* __restrict__ xb, const bf16* __restrict__ pbase,
                  const float* __restrict__ bself, bf16* __restrict__ xbT) {
  __shared__ __align__(16) char smem[69632];
  bf16* lds_a = (bf16*)smem;             // W tile [512][64], 64 KB
  bf16* lds_b = (bf16*)(smem + 65536);   // x/Psum tile [32][64], 4 KB
  const int tid  = (int)threadIdx.x;
  const int lane = tid & 63;
  const int wave = tid >> 6;             // 0..15 -> d_out rows wave*32..+31
  const int n0 = (int)blockIdx.x * 32;
  const int fr = lane & 15, fq = lane >> 4;
  const int srow = lane >> 3;
  const int scol = ((lane & 7) ^ (srow & 7)) * 8;   // pre-swizzled source slot

  f32x4 acc[2][2] = {};

  for (int pr = 0; pr < 2; ++pr) {
    const bf16* __restrict__ A = pr ? wnb : wsb;    // [512][512]
    for (int kt = 0; kt < DD / 64; ++kt) {
      const int k0 = kt * 64;
#pragma unroll
      for (int c = 0; c < 4; ++c) {
        int chunk = wave * 4 + c;
        GLDS(A + (size_t)(chunk * 8 + srow) * DD + k0 + scol, &lds_a[chunk * 512]);
      }
      if (pr == 0) {
        if (wave < 4)
          GLDS(xb + (size_t)(n0 + wave * 8 + srow) * DD + k0 + scol, &lds_b[wave * 512]);
      } else if (tid < 256) {
        // fold: Psum = sum of 4 split-K partials, staged swizzled
        int node = tid >> 3, ks = tid & 7;
        const bf16* p0 = pbase + (size_t)(n0 + node) * DD + k0 + ks * 8;
        bf16x8 v0 = *(const bf16x8*)(p0);
        bf16x8 v1 = *(const bf16x8*)(p0 + PSZE);
        bf16x8 v2 = *(const bf16x8*)(p0 + 2 * PSZE);
        bf16x8 v3 = *(const bf16x8*)(p0 + 3 * PSZE);
        bf16x8 o;
#pragma unroll
        for (int j = 0; j < 8; ++j)
          o[j] = (bf16)((float)v0[j] + (float)v1[j] + (float)v2[j] + (float)v3[j]);
        *(bf16x8*)&lds_b[node * 64 + (ks ^ (node & 7)) * 8] = o;
      }
      __syncthreads();
      bf16x8 af[2][2], bv[2][2];
#pragma unroll
      for (int kk = 0; kk < 2; ++kk) {
#pragma unroll
        for (int m = 0; m < 2; ++m) {
          int rowl = wave * 32 + m * 16 + fr;
          int slot = (kk * 4 + fq) ^ (rowl & 7);
          af[kk][m] = *(const bf16x8*)&lds_a[rowl * 64 + slot * 8];
        }
#pragma unroll
        for (int n = 0; n < 2; ++n) {
          int rowl = n * 16 + fr;
          int slot = (kk * 4 + fq) ^ (rowl & 7);
          bv[kk][n] = *(const bf16x8*)&lds_b[rowl * 64 + slot * 8];
        }
      }
#pragma unroll
      for (int kk = 0; kk < 2; ++kk)
#pragma unroll
        for (int m = 0; m < 2; ++m)
#pragma unroll
          for (int n = 0; n < 2; ++n)
            acc[m][n] = __builtin_amdgcn_mfma_f32_16x16x32_bf16(af[kk][m], bv[kk][n], acc[m][n], 0, 0, 0);
      __syncthreads();
    }
  }
  // epilogue: C'[d][node]; d = wave*32+m*16+fq*4+r, node = n0 + n*16+fr
  bf16* lds_t = (bf16*)smem;  // [32 node][520 d]
#pragma unroll
  for (int m = 0; m < 2; ++m)
#pragma unroll
    for (int n = 0; n < 2; ++n)
#pragma unroll
      for (int r = 0; r < 4; ++r) {
        int d = wave * 32 + m * 16 + fq * 4 + r;
        int node = n * 16 + fr;
        float v = acc[m][n][r] + bself[d];
        v = v > 0.f ? v : 0.f;
        bf16 h = (bf16)v;
        xbT[(size_t)d * NN + n0 + node] = h;
        lds_t[node * 520 + d] = h;
      }
  __syncthreads();
  {
    int node = tid >> 5;
    int dc = (tid & 31) * 16;
    bf16x8 v0 = *(const bf16x8*)&lds_t[node * 520 + dc];
    bf16x8 v1 = *(const bf16x8*)&lds_t[node * 520 + dc + 8];
    *(bf16x8*)&xb[(size_t)(n0 + node) * DD + dc] = v0;
    *(bf16x8*)&xb[(size_t)(n0 + node) * DD + dc + 8] = v1;
  }
}

// ---------------- pooling + head ----------------

__global__ __launch_bounds__(256) void pool_kernel(
    const bf16* __restrict__ xb, float* __restrict__ pooled) {
  const int t = (int)threadIdx.x;
  const int r0 = (int)blockIdx.x * 32;
  float s0 = 0.f, s1 = 0.f;
  for (int r = 0; r < 32; ++r) {
    s0 += (float)xb[(size_t)(r0 + r) * DD + t];
    s1 += (float)xb[(size_t)(r0 + r) * DD + t + 256];
  }
  atomicAdd(&pooled[t], s0);
  atomicAdd(&pooled[t + 256], s1);
}

__global__ __launch_bounds__(64) void final_kernel(
    const float* __restrict__ pooled, const float* __restrict__ features,
    const float* __restrict__ wfc, const float* __restrict__ bfc,
    float* __restrict__ out) {
  const int t = (int)threadIdx.x;
  float s = 0.f;
  for (int i = t; i < DD + 64; i += 64) {
    float v = (i < DD) ? pooled[i] * (1.0f / (float)NN) : features[i - DD];
    s += v * wfc[i];
  }
#pragma unroll
  for (int off = 32; off > 0; off >>= 1) s += __shfl_down(s, off);
  if (t == 0) {
    float z = s + bfc[0];
    out[0] = 1.0f / (1.0f + expf(-z));
  }
}

// ---------------- launch ----------------

extern "C" void kernel_launch(void* const* d_in, const int* in_sizes, int n_in,
                              void* d_out, int out_size, void* d_ws, size_t ws_size,
                              hipStream_t stream) {
  const float* labels   = (const float*)d_in[0];
  const float* adj      = (const float*)d_in[1];
  const float* features = (const float*)d_in[2];
  const float* W_self   = (const float*)d_in[3];
  const float* b_self   = (const float*)d_in[4];
  const float* W_neigh  = (const float*)d_in[5];
  const float* W_fc     = (const float*)d_in[6];
  const float* b_fc     = (const float*)d_in[7];
  float* out = (float*)d_out;

  char* ws = (char*)d_ws;   // ws_size = 1 GiB (observed); layout needs ~185.6 MB
  bf16*  xb    = (bf16*)(ws);
  bf16*  xbT   = (bf16*)(ws + PSZB);
  bf16*  pbase = (bf16*)(ws + 2 * PSZB);
  char*  after_p = ws + (size_t)(2 + NS) * PSZB;
  bf16*  wsb    = (bf16*)(after_p);
  bf16*  wnb    = (bf16*)(after_p + 524288);
  float* pooled = (float*)(after_p + 1048576);
  bf16*  adjb   = (bf16*)(after_p + 1048576 + 4096);

  convert_w_kernel<<<2 * DD * DD / 8 / 256, 256, 0, stream>>>(W_self, W_neigh, wsb, wnb);
  convert_adj_kernel<<<(int)((size_t)NN * NN / 8 / 256), 256, 0, stream>>>(adj, adjb);
  convert_x_kernel<<<dim3(NN / 64, DD / 64), 256, 0, stream>>>(labels, xb, xbT);

  for (int it = 0; it < 4; ++it) {
    gemm1_kernel<<<256, 512, 0, stream>>>(adjb, xbT, pbase);
    gemm2_kernel<<<NN / 32, 1024, 0, stream>>>(wsb, wnb, xb, pbase, b_self, xbT);
  }

  hipMemsetAsync(pooled, 0, DD * sizeof(float), stream);
  pool_kernel<<<NN / 32, 256, 0, stream>>>(xb, pooled);
  final_kernel<<<1, 64, 0, stream>>>(pooled, features, W_fc, b_fc, out);
}